// Round 1
// baseline (3904.741 us; speedup 1.0000x reference)
//
#include <hip/hip_runtime.h>
#include <hip/hip_bf16.h>
#include <type_traits>

// MoE MLP: B=4, L=2048, D=1024, E=8, H=4096, top-2
// T = 8192 tokens, total assignments = T*K = 16384 (always, exactly).

#define TOK  8192
#define DDIM 1024
#define NEXP 8
#define HDIM 4096
#define KSEL 2

// Workspace layout (bytes):
//  [0, 2048):    counts, strided: counts[e*64] (256B apart to kill atomic line contention)
//  [4096, +256K): tokens  int[E][TOK]
//  [OFF_W, +256K): weights float[E][TOK]
//  [1MB, ...):   h buffer, TOK*KSEL rows x HDIM (fp32 if ws fits, else bf16)
static constexpr size_t OFF_COUNTS  = 0;
static constexpr size_t OFF_TOKENS  = 4096;
static constexpr size_t OFF_WEIGHTS = OFF_TOKENS + (size_t)NEXP * TOK * 4;
static constexpr size_t OFF_H       = 1ull << 20;

// ---------------- Router ----------------
// One wave per token: logits[8] via per-lane partial dot + xor-butterfly reduce.
// top-2 renormalized weight identity: w0 = 1/(1+exp(l1-l0)).
__global__ __launch_bounds__(256) void router_k(
    const float* __restrict__ x, const float* __restrict__ Wr,
    int* __restrict__ counts, int* __restrict__ tokens, float* __restrict__ weights) {
  const int lane = threadIdx.x & 63;
  const int t = blockIdx.x * 4 + (threadIdx.x >> 6);
  const float* xr = x + (size_t)t * DDIM;

  float acc[NEXP];
#pragma unroll
  for (int e = 0; e < NEXP; ++e) acc[e] = 0.f;

#pragma unroll
  for (int it = 0; it < DDIM / 256; ++it) {   // 4 iters, lane covers 4 consecutive d
    const int d = it * 256 + lane * 4;
    const float4 xv = *(const float4*)(xr + d);
    const float* wr = Wr + (size_t)d * NEXP;
#pragma unroll
    for (int j = 0; j < 4; ++j) {
      const float xs = (j == 0) ? xv.x : (j == 1) ? xv.y : (j == 2) ? xv.z : xv.w;
      const float4 w0 = *(const float4*)(wr + j * NEXP);
      const float4 w1 = *(const float4*)(wr + j * NEXP + 4);
      acc[0] = fmaf(xs, w0.x, acc[0]); acc[1] = fmaf(xs, w0.y, acc[1]);
      acc[2] = fmaf(xs, w0.z, acc[2]); acc[3] = fmaf(xs, w0.w, acc[3]);
      acc[4] = fmaf(xs, w1.x, acc[4]); acc[5] = fmaf(xs, w1.y, acc[5]);
      acc[6] = fmaf(xs, w1.z, acc[6]); acc[7] = fmaf(xs, w1.w, acc[7]);
    }
  }
#pragma unroll
  for (int e = 0; e < NEXP; ++e) {
#pragma unroll
    for (int off = 32; off > 0; off >>= 1) acc[e] += __shfl_xor(acc[e], off);
  }
  if (lane == 0) {
    int i0 = 0; float v0 = acc[0];
#pragma unroll
    for (int e = 1; e < NEXP; ++e) if (acc[e] > v0) { v0 = acc[e]; i0 = e; }
    int i1 = -1; float v1 = -3.4e38f;
#pragma unroll
    for (int e = 0; e < NEXP; ++e) if (e != i0 && acc[e] > v1) { v1 = acc[e]; i1 = e; }
    const float r = expf(v1 - v0);          // <= 1
    const float inv = 1.f / (1.f + r);
    const float w0 = inv, w1 = r * inv;     // renormalized top-2 softmax weights
    const int p0 = atomicAdd(counts + i0 * 64, 1);
    tokens[i0 * TOK + p0] = t; weights[i0 * TOK + p0] = w0;
    const int p1 = atomicAdd(counts + i1 * 64, 1);
    tokens[i1 * TOK + p1] = t; weights[i1 * TOK + p1] = w1;
  }
}

// ---------------- Grouped GEMM1: h = silu(X_e @ W1[e]) ----------------
// 128x128 tile, 256 threads, 8x8 micro-tile, fp32 vector FMA.
template <typename HT>
__global__ __launch_bounds__(256) void gemm1_k(
    const float* __restrict__ x, const float* __restrict__ W1,
    const int* __restrict__ counts, const int* __restrict__ tokens,
    HT* __restrict__ hbuf) {
  const int e = blockIdx.z;
  const int n_e = counts[e * 64];
  const int m0 = blockIdx.y * 128;
  if (m0 >= n_e) return;
  const int n0 = blockIdx.x * 128;
  int off = 0;
#pragma unroll
  for (int i = 0; i < NEXP; ++i) off += (i < e) ? counts[i * 64] : 0;

  __shared__ float As[16][132];   // +4 pad: 16B-aligned rows, rotates banks with k
  __shared__ float Bs[16][132];

  const int tid = threadIdx.x;
  const int tx = tid & 15, ty = tid >> 4;
  const int ar = tid >> 2, akq = tid & 3;   // A staging: 64 rows x 4 float4-quarters
  const int bk = tid >> 5, bnq = tid & 31;  // B staging: 8 k-rows x 32 col-quads

  const int r0 = m0 + ar, r1 = m0 + ar + 64;
  const int tokA0 = (r0 < n_e) ? tokens[e * TOK + r0] : 0;
  const int tokA1 = (r1 < n_e) ? tokens[e * TOK + r1] : 0;
  const float* a0p = x + (size_t)tokA0 * DDIM + akq * 4;
  const float* a1p = x + (size_t)tokA1 * DDIM + akq * 4;
  const float* bp  = W1 + (size_t)e * DDIM * HDIM + (size_t)bk * HDIM + n0 + bnq * 4;

  float c[8][8];
#pragma unroll
  for (int i = 0; i < 8; ++i)
#pragma unroll
    for (int j = 0; j < 8; ++j) c[i][j] = 0.f;

  for (int kt = 0; kt < DDIM; kt += 16) {
    const float4 a0 = *(const float4*)(a0p + kt);
    const float4 a1 = *(const float4*)(a1p + kt);
    const float4 b0 = *(const float4*)(bp + (size_t)kt * HDIM);
    const float4 b1 = *(const float4*)(bp + (size_t)(kt + 8) * HDIM);
    __syncthreads();
    As[akq * 4 + 0][ar] = a0.x; As[akq * 4 + 1][ar] = a0.y;
    As[akq * 4 + 2][ar] = a0.z; As[akq * 4 + 3][ar] = a0.w;
    As[akq * 4 + 0][ar + 64] = a1.x; As[akq * 4 + 1][ar + 64] = a1.y;
    As[akq * 4 + 2][ar + 64] = a1.z; As[akq * 4 + 3][ar + 64] = a1.w;
    *(float4*)&Bs[bk][bnq * 4] = b0;
    *(float4*)&Bs[bk + 8][bnq * 4] = b1;
    __syncthreads();
#pragma unroll
    for (int k = 0; k < 16; ++k) {
      float a_[8], b_[8];
      *(float4*)&a_[0] = *(const float4*)&As[k][ty * 8];
      *(float4*)&a_[4] = *(const float4*)&As[k][ty * 8 + 4];
      *(float4*)&b_[0] = *(const float4*)&Bs[k][tx * 8];
      *(float4*)&b_[4] = *(const float4*)&Bs[k][tx * 8 + 4];
#pragma unroll
      for (int i = 0; i < 8; ++i)
#pragma unroll
        for (int j = 0; j < 8; ++j) c[i][j] = fmaf(a_[i], b_[j], c[i][j]);
    }
  }
  // epilogue: SiLU, store h row (off + r)
#pragma unroll
  for (int i = 0; i < 8; ++i) {
    const int r = m0 + ty * 8 + i;
    if (r < n_e) {
      const size_t base = (size_t)(off + r) * HDIM + n0 + tx * 8;
      float hv[8];
#pragma unroll
      for (int j = 0; j < 8; ++j) { const float v = c[i][j]; hv[j] = v / (1.f + expf(-v)); }
      if constexpr (std::is_same_v<HT, float>) {
        *(float4*)(hbuf + base)     = make_float4(hv[0], hv[1], hv[2], hv[3]);
        *(float4*)(hbuf + base + 4) = make_float4(hv[4], hv[5], hv[6], hv[7]);
      } else {
        union { __hip_bfloat16 hb[8]; uint4 pk; } u;
#pragma unroll
        for (int j = 0; j < 8; ++j) u.hb[j] = __float2bfloat16(hv[j]);
        *(uint4*)(hbuf + base) = u.pk;
      }
    }
  }
}

// ---------------- Grouped GEMM2: out[tok] += w * (h_e @ W2[e]) ----------------
template <typename HT>
__global__ __launch_bounds__(256) void gemm2_k(
    const HT* __restrict__ hbuf, const float* __restrict__ W2,
    const int* __restrict__ counts, const int* __restrict__ tokens,
    const float* __restrict__ weights, float* __restrict__ out) {
  const int e = blockIdx.z;
  const int n_e = counts[e * 64];
  const int m0 = blockIdx.y * 128;
  if (m0 >= n_e) return;
  const int n0 = blockIdx.x * 128;   // over DDIM
  int off = 0;
#pragma unroll
  for (int i = 0; i < NEXP; ++i) off += (i < e) ? counts[i * 64] : 0;

  __shared__ float As[16][132];
  __shared__ float Bs[16][132];

  const int tid = threadIdx.x;
  const int tx = tid & 15, ty = tid >> 4;
  const int ar = tid >> 2, akq = tid & 3;
  const int bk = tid >> 5, bnq = tid & 31;

  int r0 = m0 + ar;      if (r0 >= n_e) r0 = m0;   // clamp to a valid row
  int r1 = m0 + ar + 64; if (r1 >= n_e) r1 = m0;
  const HT* a0p = hbuf + (size_t)(off + r0) * HDIM + akq * 4;
  const HT* a1p = hbuf + (size_t)(off + r1) * HDIM + akq * 4;
  const float* bp = W2 + (size_t)e * HDIM * DDIM + (size_t)bk * DDIM + n0 + bnq * 4;

  float c[8][8];
#pragma unroll
  for (int i = 0; i < 8; ++i)
#pragma unroll
    for (int j = 0; j < 8; ++j) c[i][j] = 0.f;

  for (int kt = 0; kt < HDIM; kt += 16) {
    float a0[4], a1[4];
    if constexpr (std::is_same_v<HT, float>) {
      *(float4*)a0 = *(const float4*)(a0p + kt);
      *(float4*)a1 = *(const float4*)(a1p + kt);
    } else {
      const ushort4 u0 = *(const ushort4*)(a0p + kt);
      const ushort4 u1 = *(const ushort4*)(a1p + kt);
      a0[0] = __uint_as_float((unsigned)u0.x << 16); a0[1] = __uint_as_float((unsigned)u0.y << 16);
      a0[2] = __uint_as_float((unsigned)u0.z << 16); a0[3] = __uint_as_float((unsigned)u0.w << 16);
      a1[0] = __uint_as_float((unsigned)u1.x << 16); a1[1] = __uint_as_float((unsigned)u1.y << 16);
      a1[2] = __uint_as_float((unsigned)u1.z << 16); a1[3] = __uint_as_float((unsigned)u1.w << 16);
    }
    const float4 b0 = *(const float4*)(bp + (size_t)kt * DDIM);
    const float4 b1 = *(const float4*)(bp + (size_t)(kt + 8) * DDIM);
    __syncthreads();
#pragma unroll
    for (int j = 0; j < 4; ++j) {
      As[akq * 4 + j][ar] = a0[j];
      As[akq * 4 + j][ar + 64] = a1[j];
    }
    *(float4*)&Bs[bk][bnq * 4] = b0;
    *(float4*)&Bs[bk + 8][bnq * 4] = b1;
    __syncthreads();
#pragma unroll
    for (int k = 0; k < 16; ++k) {
      float a_[8], b_[8];
      *(float4*)&a_[0] = *(const float4*)&As[k][ty * 8];
      *(float4*)&a_[4] = *(const float4*)&As[k][ty * 8 + 4];
      *(float4*)&b_[0] = *(const float4*)&Bs[k][tx * 8];
      *(float4*)&b_[4] = *(const float4*)&Bs[k][tx * 8 + 4];
#pragma unroll
      for (int i = 0; i < 8; ++i)
#pragma unroll
        for (int j = 0; j < 8; ++j) c[i][j] = fmaf(a_[i], b_[j], c[i][j]);
    }
  }
#pragma unroll
  for (int i = 0; i < 8; ++i) {
    const int r = m0 + ty * 8 + i;
    if (r < n_e) {
      const int tok = tokens[e * TOK + r];
      const float w = weights[e * TOK + r];
      float* op = out + (size_t)tok * DDIM + n0 + tx * 8;
#pragma unroll
      for (int j = 0; j < 8; ++j) atomicAdd(op + j, w * c[i][j]);
    }
  }
}

// ---------------- Host launch ----------------
extern "C" void kernel_launch(void* const* d_in, const int* in_sizes, int n_in,
                              void* d_out, int out_size, void* d_ws, size_t ws_size,
                              hipStream_t stream) {
  const float* x  = (const float*)d_in[0];
  const float* Wr = (const float*)d_in[1];
  const float* W1 = (const float*)d_in[2];
  const float* W2 = (const float*)d_in[3];
  float* out = (float*)d_out;
  char* ws = (char*)d_ws;

  int*   counts  = (int*)(ws + OFF_COUNTS);
  int*   tokens  = (int*)(ws + OFF_TOKENS);
  float* weights = (float*)(ws + OFF_WEIGHTS);

  hipMemsetAsync(counts, 0, 2048, stream);
  hipMemsetAsync(d_out, 0, (size_t)out_size * sizeof(float), stream);

  router_k<<<TOK / 4, 256, 0, stream>>>(x, Wr, counts, tokens, weights);

  const dim3 g1(HDIM / 128, TOK / 128, NEXP);
  const dim3 g2(DDIM / 128, TOK / 128, NEXP);
  const size_t h_f32_bytes = (size_t)TOK * KSEL * HDIM * sizeof(float);

  if (ws_size >= OFF_H + h_f32_bytes) {
    float* hb = (float*)(ws + OFF_H);
    gemm1_k<float><<<g1, 256, 0, stream>>>(x, W1, counts, tokens, hb);
    gemm2_k<float><<<g2, 256, 0, stream>>>(hb, W2, counts, tokens, weights, out);
  } else {
    __hip_bfloat16* hb = (__hip_bfloat16*)(ws + OFF_H);
    gemm1_k<__hip_bfloat16><<<g1, 256, 0, stream>>>(x, W1, counts, tokens, hb);
    gemm2_k<__hip_bfloat16><<<g2, 256, 0, stream>>>(hb, W2, counts, tokens, weights, out);
  }
}

// Round 5
// 1225.424 us; speedup vs baseline: 3.1864x; 3.1864x over previous
//
#include <hip/hip_runtime.h>
#include <hip/hip_bf16.h>

// MoE MLP: B=4, L=2048, D=1024, E=8, H=4096, top-2. T=8192 tokens, 16384 assignments.
// Round 5 (= round 2/3/4 resubmit; bench has not run since round 1): f16 MFMA grouped
// GEMMs (16x16x32), reg-staged fp32->f16 conversion.

#define TOK  8192
#define DDIM 1024
#define NEXP 8
#define HDIM 4096

typedef __attribute__((ext_vector_type(8))) _Float16 f16x8;
typedef __attribute__((ext_vector_type(2))) _Float16 f16x2;
typedef __attribute__((ext_vector_type(4))) float    f32x4;

// Workspace layout:
//  [0,2048): counts (strided by 64 ints = 256B), [4K,+256K): tokens, then weights
//  [1MB, +128MB): h buffer, _Float16[TOK*2][HDIM]
static constexpr size_t OFF_COUNTS  = 0;
static constexpr size_t OFF_TOKENS  = 4096;
static constexpr size_t OFF_WEIGHTS = OFF_TOKENS + (size_t)NEXP * TOK * 4;
static constexpr size_t OFF_H       = 1ull << 20;

// ---------------- Router (unchanged from round 1, verified) ----------------
__global__ __launch_bounds__(256) void router_k(
    const float* __restrict__ x, const float* __restrict__ Wr,
    int* __restrict__ counts, int* __restrict__ tokens, float* __restrict__ weights) {
  const int lane = threadIdx.x & 63;
  const int t = blockIdx.x * 4 + (threadIdx.x >> 6);
  const float* xr = x + (size_t)t * DDIM;

  float acc[NEXP];
#pragma unroll
  for (int e = 0; e < NEXP; ++e) acc[e] = 0.f;

#pragma unroll
  for (int it = 0; it < DDIM / 256; ++it) {
    const int d = it * 256 + lane * 4;
    const float4 xv = *(const float4*)(xr + d);
    const float* wr = Wr + (size_t)d * NEXP;
#pragma unroll
    for (int j = 0; j < 4; ++j) {
      const float xs = (j == 0) ? xv.x : (j == 1) ? xv.y : (j == 2) ? xv.z : xv.w;
      const float4 w0 = *(const float4*)(wr + j * NEXP);
      const float4 w1 = *(const float4*)(wr + j * NEXP + 4);
      acc[0] = fmaf(xs, w0.x, acc[0]); acc[1] = fmaf(xs, w0.y, acc[1]);
      acc[2] = fmaf(xs, w0.z, acc[2]); acc[3] = fmaf(xs, w0.w, acc[3]);
      acc[4] = fmaf(xs, w1.x, acc[4]); acc[5] = fmaf(xs, w1.y, acc[5]);
      acc[6] = fmaf(xs, w1.z, acc[6]); acc[7] = fmaf(xs, w1.w, acc[7]);
    }
  }
#pragma unroll
  for (int e = 0; e < NEXP; ++e) {
#pragma unroll
    for (int off = 32; off > 0; off >>= 1) acc[e] += __shfl_xor(acc[e], off);
  }
  if (lane == 0) {
    int i0 = 0; float v0 = acc[0];
#pragma unroll
    for (int e = 1; e < NEXP; ++e) if (acc[e] > v0) { v0 = acc[e]; i0 = e; }
    int i1 = -1; float v1 = -3.4e38f;
#pragma unroll
    for (int e = 0; e < NEXP; ++e) if (e != i0 && acc[e] > v1) { v1 = acc[e]; i1 = e; }
    const float r = expf(v1 - v0);
    const float inv = 1.f / (1.f + r);
    const int p0 = atomicAdd(counts + i0 * 64, 1);
    tokens[i0 * TOK + p0] = t; weights[i0 * TOK + p0] = inv;
    const int p1 = atomicAdd(counts + i1 * 64, 1);
    tokens[i1 * TOK + p1] = t; weights[i1 * TOK + p1] = r * inv;
  }
}

// LDS tiles: [row][40] _Float16. Row stride 80B = 5 x 16B granules; gcd(5,8)=1
// -> ds_read_b128 fragment reads are low-conflict, rows stay 16B-aligned.

// ---------------- GEMM1: h = silu(gather(x) @ W1[e]), f16 MFMA ----------------
__global__ __launch_bounds__(256) void gemm1_k(
    const float* __restrict__ x, const float* __restrict__ W1,
    const int* __restrict__ counts, const int* __restrict__ tokens,
    _Float16* __restrict__ hbuf) {
  const int e = blockIdx.z;
  const int n_e = counts[e * 64];
  const int m0 = blockIdx.y * 128;
  if (m0 >= n_e) return;
  const int n0 = blockIdx.x * 128;
  int off = 0;
#pragma unroll
  for (int i = 0; i < NEXP; ++i) off += (i < e) ? counts[i * 64] : 0;

  __shared__ __align__(16) _Float16 As[128][40];
  __shared__ __align__(16) _Float16 Bs[128][40];

  const int tid = threadIdx.x;
  const int lane = tid & 63;
  const int w = tid >> 6;
  const int wr = (w >> 1) * 64, wc = (w & 1) * 64;

  // A staging: 2 threads per row, each 16 consecutive k (64B)
  const int ar = tid >> 1, aseg = (tid & 1) * 16;
  const int rA = m0 + ar;
  const int tokA = (rA < n_e) ? tokens[e * TOK + rA] : 0;
  const float* aP = x + (size_t)tokA * DDIM + aseg;
  // B staging: thread covers 4 k-rows x 4 n (transpose into Bs[n][k])
  const int bk4 = (tid >> 5) * 4, bn4 = (tid & 31) * 4;
  const float* bP = W1 + (size_t)e * DDIM * HDIM + (size_t)bk4 * HDIM + n0 + bn4;

  f32x4 acc[4][4] = {};

  float4 av[4], bv[4];
#pragma unroll
  for (int j = 0; j < 4; ++j) av[j] = *(const float4*)(aP + j * 4);
#pragma unroll
  for (int j = 0; j < 4; ++j) bv[j] = *(const float4*)(bP + (size_t)j * HDIM);

  for (int kt = 0; kt < DDIM; kt += 32) {
    __syncthreads();
    {
      unsigned u[8];
#pragma unroll
      for (int j = 0; j < 4; ++j) {
        u[j * 2]     = __builtin_bit_cast(unsigned, __builtin_amdgcn_cvt_pkrtz(av[j].x, av[j].y));
        u[j * 2 + 1] = __builtin_bit_cast(unsigned, __builtin_amdgcn_cvt_pkrtz(av[j].z, av[j].w));
      }
      *(uint4*)&As[ar][aseg]     = make_uint4(u[0], u[1], u[2], u[3]);
      *(uint4*)&As[ar][aseg + 8] = make_uint4(u[4], u[5], u[6], u[7]);
      const float* f0 = (const float*)&bv[0];
      const float* f1 = (const float*)&bv[1];
      const float* f2 = (const float*)&bv[2];
      const float* f3 = (const float*)&bv[3];
#pragma unroll
      for (int i = 0; i < 4; ++i) {
        const unsigned p0 = __builtin_bit_cast(unsigned, __builtin_amdgcn_cvt_pkrtz(f0[i], f1[i]));
        const unsigned p1 = __builtin_bit_cast(unsigned, __builtin_amdgcn_cvt_pkrtz(f2[i], f3[i]));
        *(uint2*)&Bs[bn4 + i][bk4] = make_uint2(p0, p1);
      }
    }
    __syncthreads();
    if (kt + 32 < DDIM) {
#pragma unroll
      for (int j = 0; j < 4; ++j) av[j] = *(const float4*)(aP + kt + 32 + j * 4);
#pragma unroll
      for (int j = 0; j < 4; ++j) bv[j] = *(const float4*)(bP + (size_t)(kt + 32 + j) * HDIM);
    }
    const int l15 = lane & 15, g8 = (lane >> 4) * 8;
    f16x8 af[4], bf[4];
#pragma unroll
    for (int mf = 0; mf < 4; ++mf) af[mf] = *(const f16x8*)&As[wr + mf * 16 + l15][g8];
#pragma unroll
    for (int nf = 0; nf < 4; ++nf) bf[nf] = *(const f16x8*)&Bs[wc + nf * 16 + l15][g8];
#pragma unroll
    for (int mf = 0; mf < 4; ++mf)
#pragma unroll
      for (int nf = 0; nf < 4; ++nf)
        acc[mf][nf] = __builtin_amdgcn_mfma_f32_16x16x32_f16(af[mf], bf[nf], acc[mf][nf], 0, 0, 0);
  }

  // epilogue: SiLU -> f16 h rows. C/D layout: col=lane&15, row=(lane>>4)*4+q.
  const int l15 = lane & 15, rq = (lane >> 4) * 4;
#pragma unroll
  for (int mf = 0; mf < 4; ++mf) {
#pragma unroll
    for (int q = 0; q < 4; ++q) {
      const int r = m0 + wr + mf * 16 + rq + q;
      if (r < n_e) {
        _Float16* hp = hbuf + (size_t)(off + r) * HDIM + n0 + wc + l15;
#pragma unroll
        for (int nf = 0; nf < 4; ++nf) {
          const float v = acc[mf][nf][q];
          hp[nf * 16] = (_Float16)(v / (1.f + __expf(-v)));
        }
      }
    }
  }
}

// ---------------- GEMM2: out[tok] += w * (h_e @ W2[e]), f16 MFMA ----------------
__global__ __launch_bounds__(256) void gemm2_k(
    const _Float16* __restrict__ hbuf, const float* __restrict__ W2,
    const int* __restrict__ counts, const int* __restrict__ tokens,
    const float* __restrict__ weights, float* __restrict__ out) {
  const int e = blockIdx.z;
  const int n_e = counts[e * 64];
  const int m0 = blockIdx.y * 128;
  if (m0 >= n_e) return;
  const int n0 = blockIdx.x * 128;
  int off = 0;
#pragma unroll
  for (int i = 0; i < NEXP; ++i) off += (i < e) ? counts[i * 64] : 0;

  __shared__ __align__(16) _Float16 As[128][40];
  __shared__ __align__(16) _Float16 Bs[128][40];

  const int tid = threadIdx.x;
  const int lane = tid & 63;
  const int w = tid >> 6;
  const int wr = (w >> 1) * 64, wc = (w & 1) * 64;

  const int ar = tid >> 1, aseg = (tid & 1) * 16;
  int rA = m0 + ar; if (rA >= n_e) rA = m0;   // clamp to a valid h row
  const _Float16* aP = hbuf + (size_t)(off + rA) * HDIM + aseg;
  const int bk4 = (tid >> 5) * 4, bn4 = (tid & 31) * 4;
  const float* bP = W2 + (size_t)e * HDIM * DDIM + (size_t)bk4 * DDIM + n0 + bn4;

  f32x4 acc[4][4] = {};

  uint4 av[2]; float4 bv[4];
  av[0] = *(const uint4*)(aP);
  av[1] = *(const uint4*)(aP + 8);
#pragma unroll
  for (int j = 0; j < 4; ++j) bv[j] = *(const float4*)(bP + (size_t)j * DDIM);

  for (int kt = 0; kt < HDIM; kt += 32) {
    __syncthreads();
    {
      *(uint4*)&As[ar][aseg]     = av[0];
      *(uint4*)&As[ar][aseg + 8] = av[1];
      const float* f0 = (const float*)&bv[0];
      const float* f1 = (const float*)&bv[1];
      const float* f2 = (const float*)&bv[2];
      const float* f3 = (const float*)&bv[3];
#pragma unroll
      for (int i = 0; i < 4; ++i) {
        const unsigned p0 = __builtin_bit_cast(unsigned, __builtin_amdgcn_cvt_pkrtz(f0[i], f1[i]));
        const unsigned p1 = __builtin_bit_cast(unsigned, __builtin_amdgcn_cvt_pkrtz(f2[i], f3[i]));
        *(uint2*)&Bs[bn4 + i][bk4] = make_uint2(p0, p1);
      }
    }
    __syncthreads();
    if (kt + 32 < HDIM) {
      av[0] = *(const uint4*)(aP + kt + 32);
      av[1] = *(const uint4*)(aP + kt + 32 + 8);
#pragma unroll
      for (int j = 0; j < 4; ++j) bv[j] = *(const float4*)(bP + (size_t)(kt + 32 + j) * DDIM);
    }
    const int l15 = lane & 15, g8 = (lane >> 4) * 8;
    f16x8 af[4], bf[4];
#pragma unroll
    for (int mf = 0; mf < 4; ++mf) af[mf] = *(const f16x8*)&As[wr + mf * 16 + l15][g8];
#pragma unroll
    for (int nf = 0; nf < 4; ++nf) bf[nf] = *(const f16x8*)&Bs[wc + nf * 16 + l15][g8];
#pragma unroll
    for (int mf = 0; mf < 4; ++mf)
#pragma unroll
      for (int nf = 0; nf < 4; ++nf)
        acc[mf][nf] = __builtin_amdgcn_mfma_f32_16x16x32_f16(af[mf], bf[nf], acc[mf][nf], 0, 0, 0);
  }

  const int l15 = lane & 15, rq = (lane >> 4) * 4;
#pragma unroll
  for (int mf = 0; mf < 4; ++mf) {
#pragma unroll
    for (int q = 0; q < 4; ++q) {
      const int r = m0 + wr + mf * 16 + rq + q;
      if (r < n_e) {
        const int tok = tokens[e * TOK + r];
        const float wgt = weights[e * TOK + r];
        float* op = out + (size_t)tok * DDIM + n0 + wc + l15;
#pragma unroll
        for (int nf = 0; nf < 4; ++nf) atomicAdd(op + nf * 16, wgt * acc[mf][nf][q]);
      }
    }
  }
}

// ---------------- Host launch ----------------
extern "C" void kernel_launch(void* const* d_in, const int* in_sizes, int n_in,
                              void* d_out, int out_size, void* d_ws, size_t ws_size,
                              hipStream_t stream) {
  const float* x  = (const float*)d_in[0];
  const float* Wr = (const float*)d_in[1];
  const float* W1 = (const float*)d_in[2];
  const float* W2 = (const float*)d_in[3];
  float* out = (float*)d_out;
  char* ws = (char*)d_ws;

  int*   counts  = (int*)(ws + OFF_COUNTS);
  int*   tokens  = (int*)(ws + OFF_TOKENS);
  float* weights = (float*)(ws + OFF_WEIGHTS);
  _Float16* hbuf = (_Float16*)(ws + OFF_H);

  hipMemsetAsync(counts, 0, 2048, stream);
  hipMemsetAsync(d_out, 0, (size_t)out_size * sizeof(float), stream);

  router_k<<<TOK / 4, 256, 0, stream>>>(x, Wr, counts, tokens, weights);

  const dim3 g1(HDIM / 128, TOK / 128, NEXP);
  const dim3 g2(DDIM / 128, TOK / 128, NEXP);
  gemm1_k<<<g1, 256, 0, stream>>>(x, W1, counts, tokens, hbuf);
  gemm2_k<<<g2, 256, 0, stream>>>(hbuf, W2, counts, tokens, weights, out);
}

// Round 6
// 1211.257 us; speedup vs baseline: 3.2237x; 1.0117x over previous
//
#include <hip/hip_runtime.h>
#include <hip/hip_bf16.h>

// MoE MLP: B=4, L=2048, D=1024, E=8, H=4096, top-2. T=8192 tokens, 16384 assignments.
// Round 6: round-5 f16-MFMA structure + (1) 2-deep register prefetch across RAW
// barriers (no compiler vmcnt(0) drain), (2) Bs transpose-staging re-map to cut
// 16-way ds_write conflicts to 4-way.

#define TOK  8192
#define DDIM 1024
#define NEXP 8
#define HDIM 4096

typedef __attribute__((ext_vector_type(8))) _Float16 f16x8;
typedef __attribute__((ext_vector_type(4))) float    f32x4;

static constexpr size_t OFF_COUNTS  = 0;
static constexpr size_t OFF_TOKENS  = 4096;
static constexpr size_t OFF_WEIGHTS = OFF_TOKENS + (size_t)NEXP * TOK * 4;
static constexpr size_t OFF_H       = 1ull << 20;

// lgkmcnt(0) (LDS writes/reads drained) + s_barrier, WITHOUT the vmcnt(0) drain
// hipcc emits for __syncthreads(). Register-staged global loads stay in flight;
// the compiler inserts counted vmcnt(N) waits only where the data is consumed.
#define FENCE_BAR asm volatile("s_waitcnt lgkmcnt(0)\n\ts_barrier" ::: "memory")

// ---------------- Router (verified rounds 1/5) ----------------
__global__ __launch_bounds__(256) void router_k(
    const float* __restrict__ x, const float* __restrict__ Wr,
    int* __restrict__ counts, int* __restrict__ tokens, float* __restrict__ weights) {
  const int lane = threadIdx.x & 63;
  const int t = blockIdx.x * 4 + (threadIdx.x >> 6);
  const float* xr = x + (size_t)t * DDIM;

  float acc[NEXP];
#pragma unroll
  for (int e = 0; e < NEXP; ++e) acc[e] = 0.f;

#pragma unroll
  for (int it = 0; it < DDIM / 256; ++it) {
    const int d = it * 256 + lane * 4;
    const float4 xv = *(const float4*)(xr + d);
    const float* wr = Wr + (size_t)d * NEXP;
#pragma unroll
    for (int j = 0; j < 4; ++j) {
      const float xs = (j == 0) ? xv.x : (j == 1) ? xv.y : (j == 2) ? xv.z : xv.w;
      const float4 w0 = *(const float4*)(wr + j * NEXP);
      const float4 w1 = *(const float4*)(wr + j * NEXP + 4);
      acc[0] = fmaf(xs, w0.x, acc[0]); acc[1] = fmaf(xs, w0.y, acc[1]);
      acc[2] = fmaf(xs, w0.z, acc[2]); acc[3] = fmaf(xs, w0.w, acc[3]);
      acc[4] = fmaf(xs, w1.x, acc[4]); acc[5] = fmaf(xs, w1.y, acc[5]);
      acc[6] = fmaf(xs, w1.z, acc[6]); acc[7] = fmaf(xs, w1.w, acc[7]);
    }
  }
#pragma unroll
  for (int e = 0; e < NEXP; ++e) {
#pragma unroll
    for (int off = 32; off > 0; off >>= 1) acc[e] += __shfl_xor(acc[e], off);
  }
  if (lane == 0) {
    int i0 = 0; float v0 = acc[0];
#pragma unroll
    for (int e = 1; e < NEXP; ++e) if (acc[e] > v0) { v0 = acc[e]; i0 = e; }
    int i1 = -1; float v1 = -3.4e38f;
#pragma unroll
    for (int e = 0; e < NEXP; ++e) if (e != i0 && acc[e] > v1) { v1 = acc[e]; i1 = e; }
    const float r = expf(v1 - v0);
    const float inv = 1.f / (1.f + r);
    const int p0 = atomicAdd(counts + i0 * 64, 1);
    tokens[i0 * TOK + p0] = t; weights[i0 * TOK + p0] = inv;
    const int p1 = atomicAdd(counts + i1 * 64, 1);
    tokens[i1 * TOK + p1] = t; weights[i1 * TOK + p1] = r * inv;
  }
}

// LDS tiles [row][40] f16 (80B stride): fragment ds_read_b128 conflict-free
// (verified round 5); B-writes now 4-way (rows stride-1 per lane).

// B loads: thread owns n-rows {bn, bn+32, bn+64, bn+96} x k {bk4..bk4+3};
// per (g,j) a coalesced dword across lanes (32 consecutive n = 128B).
template <int LD>
__device__ __forceinline__ void b_load(const float* bP, int kt, float (&bv)[4][4]) {
#pragma unroll
  for (int g = 0; g < 4; ++g)
#pragma unroll
    for (int j = 0; j < 4; ++j)
      bv[g][j] = bP[(size_t)(kt + j) * LD + 32 * g];
}

__device__ __forceinline__ void b_store(int bn, int bk4, const float (&bv)[4][4],
                                        _Float16 (*Bs)[40]) {
#pragma unroll
  for (int g = 0; g < 4; ++g) {
    const unsigned p0 = __builtin_bit_cast(unsigned, __builtin_amdgcn_cvt_pkrtz(bv[g][0], bv[g][1]));
    const unsigned p1 = __builtin_bit_cast(unsigned, __builtin_amdgcn_cvt_pkrtz(bv[g][2], bv[g][3]));
    *(uint2*)&Bs[bn + 32 * g][bk4] = make_uint2(p0, p1);
  }
}

// Fragment read + 16 MFMA (layouts verified on HW in round 5).
__device__ __forceinline__ void g_compute(const _Float16 (*As)[40], const _Float16 (*Bs)[40],
                                          int wr, int wc, int lane, f32x4 (&acc)[4][4]) {
  const int l15 = lane & 15, g8 = (lane >> 4) * 8;
  f16x8 af[4], bf[4];
#pragma unroll
  for (int mf = 0; mf < 4; ++mf) af[mf] = *(const f16x8*)&As[wr + mf * 16 + l15][g8];
#pragma unroll
  for (int nf = 0; nf < 4; ++nf) bf[nf] = *(const f16x8*)&Bs[wc + nf * 16 + l15][g8];
#pragma unroll
  for (int mf = 0; mf < 4; ++mf)
#pragma unroll
    for (int nf = 0; nf < 4; ++nf)
      acc[mf][nf] = __builtin_amdgcn_mfma_f32_16x16x32_f16(af[mf], bf[nf], acc[mf][nf], 0, 0, 0);
}

// ---------------- GEMM1: h = silu(gather(x) @ W1[e]) ----------------
__global__ __launch_bounds__(256, 2) void gemm1_k(
    const float* __restrict__ x, const float* __restrict__ W1,
    const int* __restrict__ counts, const int* __restrict__ tokens,
    _Float16* __restrict__ hbuf) {
  const int e = blockIdx.z;
  const int n_e = counts[e * 64];
  const int m0 = blockIdx.y * 128;
  if (m0 >= n_e) return;
  const int n0 = blockIdx.x * 128;
  int off = 0;
#pragma unroll
  for (int i = 0; i < NEXP; ++i) off += (i < e) ? counts[i * 64] : 0;

  __shared__ __align__(16) _Float16 As[128][40];
  __shared__ __align__(16) _Float16 Bs[128][40];

  const int tid = threadIdx.x;
  const int lane = tid & 63;
  const int w = tid >> 6;
  const int wr = (w >> 1) * 64, wc = (w & 1) * 64;

  const int ar = tid >> 1, aseg = (tid & 1) * 16;
  const int rA = m0 + ar;
  const int tokA = (rA < n_e) ? tokens[e * TOK + rA] : 0;
  const float* aP = x + (size_t)tokA * DDIM + aseg;
  const int bn = tid & 31, bk4 = (tid >> 5) * 4;
  const float* bP = W1 + (size_t)e * DDIM * HDIM + (size_t)bk4 * HDIM + n0 + bn;

  f32x4 acc[4][4] = {};

  float4 av0[4], av1[4];
  float  bv0[4][4], bv1[4][4];
#pragma unroll
  for (int j = 0; j < 4; ++j) av0[j] = *(const float4*)(aP + j * 4);
  b_load<HDIM>(bP, 0, bv0);
#pragma unroll
  for (int j = 0; j < 4; ++j) av1[j] = *(const float4*)(aP + 32 + j * 4);
  b_load<HDIM>(bP, 32, bv1);

  for (int kt = 0; kt < DDIM; kt += 64) {
    // ---- half 0: consume slot0, refill for kt+64 ----
    {
      unsigned u[8];
#pragma unroll
      for (int j = 0; j < 4; ++j) {
        u[j * 2]     = __builtin_bit_cast(unsigned, __builtin_amdgcn_cvt_pkrtz(av0[j].x, av0[j].y));
        u[j * 2 + 1] = __builtin_bit_cast(unsigned, __builtin_amdgcn_cvt_pkrtz(av0[j].z, av0[j].w));
      }
      *(uint4*)&As[ar][aseg]     = make_uint4(u[0], u[1], u[2], u[3]);
      *(uint4*)&As[ar][aseg + 8] = make_uint4(u[4], u[5], u[6], u[7]);
      b_store(bn, bk4, bv0, Bs);
    }
    if (kt + 64 < DDIM) {
#pragma unroll
      for (int j = 0; j < 4; ++j) av0[j] = *(const float4*)(aP + kt + 64 + j * 4);
      b_load<HDIM>(bP, kt + 64, bv0);
    }
    FENCE_BAR;
    g_compute(As, Bs, wr, wc, lane, acc);
    FENCE_BAR;
    // ---- half 1: consume slot1, refill for kt+96 ----
    {
      unsigned u[8];
#pragma unroll
      for (int j = 0; j < 4; ++j) {
        u[j * 2]     = __builtin_bit_cast(unsigned, __builtin_amdgcn_cvt_pkrtz(av1[j].x, av1[j].y));
        u[j * 2 + 1] = __builtin_bit_cast(unsigned, __builtin_amdgcn_cvt_pkrtz(av1[j].z, av1[j].w));
      }
      *(uint4*)&As[ar][aseg]     = make_uint4(u[0], u[1], u[2], u[3]);
      *(uint4*)&As[ar][aseg + 8] = make_uint4(u[4], u[5], u[6], u[7]);
      b_store(bn, bk4, bv1, Bs);
    }
    if (kt + 96 < DDIM) {
#pragma unroll
      for (int j = 0; j < 4; ++j) av1[j] = *(const float4*)(aP + kt + 96 + j * 4);
      b_load<HDIM>(bP, kt + 96, bv1);
    }
    FENCE_BAR;
    g_compute(As, Bs, wr, wc, lane, acc);
    FENCE_BAR;
  }

  // epilogue: SiLU -> f16 h rows. C/D layout: col=lane&15, row=(lane>>4)*4+q.
  const int l15 = lane & 15, rq = (lane >> 4) * 4;
#pragma unroll
  for (int mf = 0; mf < 4; ++mf) {
#pragma unroll
    for (int q = 0; q < 4; ++q) {
      const int r = m0 + wr + mf * 16 + rq + q;
      if (r < n_e) {
        _Float16* hp = hbuf + (size_t)(off + r) * HDIM + n0 + wc + l15;
#pragma unroll
        for (int nf = 0; nf < 4; ++nf) {
          const float v = acc[mf][nf][q];
          hp[nf * 16] = (_Float16)(v / (1.f + __expf(-v)));
        }
      }
    }
  }
}

// ---------------- GEMM2: out[tok] += w * (h_e @ W2[e]) ----------------
__global__ __launch_bounds__(256, 2) void gemm2_k(
    const _Float16* __restrict__ hbuf, const float* __restrict__ W2,
    const int* __restrict__ counts, const int* __restrict__ tokens,
    const float* __restrict__ weights, float* __restrict__ out) {
  const int e = blockIdx.z;
  const int n_e = counts[e * 64];
  const int m0 = blockIdx.y * 128;
  if (m0 >= n_e) return;
  const int n0 = blockIdx.x * 128;
  int off = 0;
#pragma unroll
  for (int i = 0; i < NEXP; ++i) off += (i < e) ? counts[i * 64] : 0;

  __shared__ __align__(16) _Float16 As[128][40];
  __shared__ __align__(16) _Float16 Bs[128][40];

  const int tid = threadIdx.x;
  const int lane = tid & 63;
  const int w = tid >> 6;
  const int wr = (w >> 1) * 64, wc = (w & 1) * 64;

  const int ar = tid >> 1, aseg = (tid & 1) * 16;
  int rA = m0 + ar; if (rA >= n_e) rA = m0;   // clamp to a valid h row
  const _Float16* aP = hbuf + (size_t)(off + rA) * HDIM + aseg;
  const int bn = tid & 31, bk4 = (tid >> 5) * 4;
  const float* bP = W2 + (size_t)e * HDIM * DDIM + (size_t)bk4 * DDIM + n0 + bn;

  f32x4 acc[4][4] = {};

  uint4 av0[2], av1[2];
  float bv0[4][4], bv1[4][4];
  av0[0] = *(const uint4*)(aP);      av0[1] = *(const uint4*)(aP + 8);
  b_load<DDIM>(bP, 0, bv0);
  av1[0] = *(const uint4*)(aP + 32); av1[1] = *(const uint4*)(aP + 40);
  b_load<DDIM>(bP, 32, bv1);

  for (int kt = 0; kt < HDIM; kt += 64) {
    {
      *(uint4*)&As[ar][aseg]     = av0[0];
      *(uint4*)&As[ar][aseg + 8] = av0[1];
      b_store(bn, bk4, bv0, Bs);
    }
    if (kt + 64 < HDIM) {
      av0[0] = *(const uint4*)(aP + kt + 64);
      av0[1] = *(const uint4*)(aP + kt + 72);
      b_load<DDIM>(bP, kt + 64, bv0);
    }
    FENCE_BAR;
    g_compute(As, Bs, wr, wc, lane, acc);
    FENCE_BAR;
    {
      *(uint4*)&As[ar][aseg]     = av1[0];
      *(uint4*)&As[ar][aseg + 8] = av1[1];
      b_store(bn, bk4, bv1, Bs);
    }
    if (kt + 96 < HDIM) {
      av1[0] = *(const uint4*)(aP + kt + 96);
      av1[1] = *(const uint4*)(aP + kt + 104);
      b_load<DDIM>(bP, kt + 96, bv1);
    }
    FENCE_BAR;
    g_compute(As, Bs, wr, wc, lane, acc);
    FENCE_BAR;
  }

  const int l15 = lane & 15, rq = (lane >> 4) * 4;
#pragma unroll
  for (int mf = 0; mf < 4; ++mf) {
#pragma unroll
    for (int q = 0; q < 4; ++q) {
      const int r = m0 + wr + mf * 16 + rq + q;
      if (r < n_e) {
        const int tok = tokens[e * TOK + r];
        const float wgt = weights[e * TOK + r];
        float* op = out + (size_t)tok * DDIM + n0 + wc + l15;
#pragma unroll
        for (int nf = 0; nf < 4; ++nf) atomicAdd(op + nf * 16, wgt * acc[mf][nf][q]);
      }
    }
  }
}

// ---------------- Host launch ----------------
extern "C" void kernel_launch(void* const* d_in, const int* in_sizes, int n_in,
                              void* d_out, int out_size, void* d_ws, size_t ws_size,
                              hipStream_t stream) {
  const float* x  = (const float*)d_in[0];
  const float* Wr = (const float*)d_in[1];
  const float* W1 = (const float*)d_in[2];
  const float* W2 = (const float*)d_in[3];
  float* out = (float*)d_out;
  char* ws = (char*)d_ws;

  int*   counts  = (int*)(ws + OFF_COUNTS);
  int*   tokens  = (int*)(ws + OFF_TOKENS);
  float* weights = (float*)(ws + OFF_WEIGHTS);
  _Float16* hbuf = (_Float16*)(ws + OFF_H);

  hipMemsetAsync(counts, 0, 2048, stream);
  hipMemsetAsync(d_out, 0, (size_t)out_size * sizeof(float), stream);

  router_k<<<TOK / 4, 256, 0, stream>>>(x, Wr, counts, tokens, weights);

  const dim3 g1(HDIM / 128, TOK / 128, NEXP);
  const dim3 g2(DDIM / 128, TOK / 128, NEXP);
  gemm1_k<<<g1, 256, 0, stream>>>(x, W1, counts, tokens, hbuf);
  gemm2_k<<<g2, 256, 0, stream>>>(hbuf, W2, counts, tokens, weights, out);
}

// Round 7
// 1190.169 us; speedup vs baseline: 3.2808x; 1.0177x over previous
//
#include <hip/hip_runtime.h>
#include <hip/hip_bf16.h>

// MoE MLP: B=4, L=2048, D=1024, E=8, H=4096, top-2. T=8192 tokens, 16384 assignments.
// Round 7: kill gemm2's atomicAdd scatter (measured 1.7 GB of HBM RMW traffic).
// gemm2 now writes per-assignment y rows (f16); new combine_k gathers
// out[t] = w0*y[slot0] + w1*y[slot1]. Router records slot map.

#define TOK  8192
#define DDIM 1024
#define NEXP 8
#define HDIM 4096

typedef __attribute__((ext_vector_type(8))) _Float16 f16x8;
typedef __attribute__((ext_vector_type(4))) float    f32x4;

static constexpr size_t OFF_COUNTS  = 0;
static constexpr size_t OFF_TOKENS  = 4096;
static constexpr size_t OFF_WEIGHTS = OFF_TOKENS + (size_t)NEXP * TOK * 4;      // 256KB
static constexpr size_t OFF_SLOTS   = OFF_WEIGHTS + (size_t)NEXP * TOK * 4;     // 256KB
static constexpr size_t OFF_H       = 1ull << 20;                               // 1MB
static constexpr size_t OFF_Y       = OFF_H + (1ull << 27);                     // 1MB+128MB

// lgkmcnt(0)+barrier without the vmcnt(0) drain __syncthreads() would emit.
#define FENCE_BAR asm volatile("s_waitcnt lgkmcnt(0)\n\ts_barrier" ::: "memory")

// ---------------- Router ----------------
__global__ __launch_bounds__(256) void router_k(
    const float* __restrict__ x, const float* __restrict__ Wr,
    int* __restrict__ counts, int* __restrict__ tokens, float* __restrict__ weights,
    int* __restrict__ slots) {
  const int lane = threadIdx.x & 63;
  const int t = blockIdx.x * 4 + (threadIdx.x >> 6);
  const float* xr = x + (size_t)t * DDIM;

  float acc[NEXP];
#pragma unroll
  for (int e = 0; e < NEXP; ++e) acc[e] = 0.f;

#pragma unroll
  for (int it = 0; it < DDIM / 256; ++it) {
    const int d = it * 256 + lane * 4;
    const float4 xv = *(const float4*)(xr + d);
    const float* wr = Wr + (size_t)d * NEXP;
#pragma unroll
    for (int j = 0; j < 4; ++j) {
      const float xs = (j == 0) ? xv.x : (j == 1) ? xv.y : (j == 2) ? xv.z : xv.w;
      const float4 w0 = *(const float4*)(wr + j * NEXP);
      const float4 w1 = *(const float4*)(wr + j * NEXP + 4);
      acc[0] = fmaf(xs, w0.x, acc[0]); acc[1] = fmaf(xs, w0.y, acc[1]);
      acc[2] = fmaf(xs, w0.z, acc[2]); acc[3] = fmaf(xs, w0.w, acc[3]);
      acc[4] = fmaf(xs, w1.x, acc[4]); acc[5] = fmaf(xs, w1.y, acc[5]);
      acc[6] = fmaf(xs, w1.z, acc[6]); acc[7] = fmaf(xs, w1.w, acc[7]);
    }
  }
#pragma unroll
  for (int e = 0; e < NEXP; ++e) {
#pragma unroll
    for (int off = 32; off > 0; off >>= 1) acc[e] += __shfl_xor(acc[e], off);
  }
  if (lane == 0) {
    int i0 = 0; float v0 = acc[0];
#pragma unroll
    for (int e = 1; e < NEXP; ++e) if (acc[e] > v0) { v0 = acc[e]; i0 = e; }
    int i1 = -1; float v1 = -3.4e38f;
#pragma unroll
    for (int e = 0; e < NEXP; ++e) if (e != i0 && acc[e] > v1) { v1 = acc[e]; i1 = e; }
    const float r = expf(v1 - v0);
    const float inv = 1.f / (1.f + r);
    const int p0 = atomicAdd(counts + i0 * 64, 1);
    tokens[i0 * TOK + p0] = t; weights[i0 * TOK + p0] = inv;
    const int p1 = atomicAdd(counts + i1 * 64, 1);
    tokens[i1 * TOK + p1] = t; weights[i1 * TOK + p1] = r * inv;
    slots[t * 2]     = (i0 << 16) | p0;
    slots[t * 2 + 1] = (i1 << 16) | p1;
  }
}

// LDS tiles [row][40] f16 (80B stride): fragment ds_read_b128 conflict-free;
// B transpose-staging writes 4-way (verified round 6).

template <int LD>
__device__ __forceinline__ void b_load(const float* bP, int kt, float (&bv)[4][4]) {
#pragma unroll
  for (int g = 0; g < 4; ++g)
#pragma unroll
    for (int j = 0; j < 4; ++j)
      bv[g][j] = bP[(size_t)(kt + j) * LD + 32 * g];
}

__device__ __forceinline__ void b_store(int bn, int bk4, const float (&bv)[4][4],
                                        _Float16 (*Bs)[40]) {
#pragma unroll
  for (int g = 0; g < 4; ++g) {
    const unsigned p0 = __builtin_bit_cast(unsigned, __builtin_amdgcn_cvt_pkrtz(bv[g][0], bv[g][1]));
    const unsigned p1 = __builtin_bit_cast(unsigned, __builtin_amdgcn_cvt_pkrtz(bv[g][2], bv[g][3]));
    *(uint2*)&Bs[bn + 32 * g][bk4] = make_uint2(p0, p1);
  }
}

__device__ __forceinline__ void g_compute(const _Float16 (*As)[40], const _Float16 (*Bs)[40],
                                          int wr, int wc, int lane, f32x4 (&acc)[4][4]) {
  const int l15 = lane & 15, g8 = (lane >> 4) * 8;
  f16x8 af[4], bf[4];
#pragma unroll
  for (int mf = 0; mf < 4; ++mf) af[mf] = *(const f16x8*)&As[wr + mf * 16 + l15][g8];
#pragma unroll
  for (int nf = 0; nf < 4; ++nf) bf[nf] = *(const f16x8*)&Bs[wc + nf * 16 + l15][g8];
#pragma unroll
  for (int mf = 0; mf < 4; ++mf)
#pragma unroll
    for (int nf = 0; nf < 4; ++nf)
      acc[mf][nf] = __builtin_amdgcn_mfma_f32_16x16x32_f16(af[mf], bf[nf], acc[mf][nf], 0, 0, 0);
}

// ---------------- GEMM1: h = silu(gather(x) @ W1[e]) ----------------
__global__ __launch_bounds__(256, 2) void gemm1_k(
    const float* __restrict__ x, const float* __restrict__ W1,
    const int* __restrict__ counts, const int* __restrict__ tokens,
    _Float16* __restrict__ hbuf) {
  const int e = blockIdx.z;
  const int n_e = counts[e * 64];
  const int m0 = blockIdx.y * 128;
  if (m0 >= n_e) return;
  const int n0 = blockIdx.x * 128;
  int off = 0;
#pragma unroll
  for (int i = 0; i < NEXP; ++i) off += (i < e) ? counts[i * 64] : 0;

  __shared__ __align__(16) _Float16 As[128][40];
  __shared__ __align__(16) _Float16 Bs[128][40];

  const int tid = threadIdx.x;
  const int lane = tid & 63;
  const int w = tid >> 6;
  const int wr = (w >> 1) * 64, wc = (w & 1) * 64;

  const int ar = tid >> 1, aseg = (tid & 1) * 16;
  const int rA = m0 + ar;
  const int tokA = (rA < n_e) ? tokens[e * TOK + rA] : 0;
  const float* aP = x + (size_t)tokA * DDIM + aseg;
  const int bn = tid & 31, bk4 = (tid >> 5) * 4;
  const float* bP = W1 + (size_t)e * DDIM * HDIM + (size_t)bk4 * HDIM + n0 + bn;

  f32x4 acc[4][4] = {};

  float4 av0[4], av1[4];
  float  bv0[4][4], bv1[4][4];
#pragma unroll
  for (int j = 0; j < 4; ++j) av0[j] = *(const float4*)(aP + j * 4);
  b_load<HDIM>(bP, 0, bv0);
#pragma unroll
  for (int j = 0; j < 4; ++j) av1[j] = *(const float4*)(aP + 32 + j * 4);
  b_load<HDIM>(bP, 32, bv1);

  for (int kt = 0; kt < DDIM; kt += 64) {
    {
      unsigned u[8];
#pragma unroll
      for (int j = 0; j < 4; ++j) {
        u[j * 2]     = __builtin_bit_cast(unsigned, __builtin_amdgcn_cvt_pkrtz(av0[j].x, av0[j].y));
        u[j * 2 + 1] = __builtin_bit_cast(unsigned, __builtin_amdgcn_cvt_pkrtz(av0[j].z, av0[j].w));
      }
      *(uint4*)&As[ar][aseg]     = make_uint4(u[0], u[1], u[2], u[3]);
      *(uint4*)&As[ar][aseg + 8] = make_uint4(u[4], u[5], u[6], u[7]);
      b_store(bn, bk4, bv0, Bs);
    }
    if (kt + 64 < DDIM) {
#pragma unroll
      for (int j = 0; j < 4; ++j) av0[j] = *(const float4*)(aP + kt + 64 + j * 4);
      b_load<HDIM>(bP, kt + 64, bv0);
    }
    FENCE_BAR;
    g_compute(As, Bs, wr, wc, lane, acc);
    FENCE_BAR;
    {
      unsigned u[8];
#pragma unroll
      for (int j = 0; j < 4; ++j) {
        u[j * 2]     = __builtin_bit_cast(unsigned, __builtin_amdgcn_cvt_pkrtz(av1[j].x, av1[j].y));
        u[j * 2 + 1] = __builtin_bit_cast(unsigned, __builtin_amdgcn_cvt_pkrtz(av1[j].z, av1[j].w));
      }
      *(uint4*)&As[ar][aseg]     = make_uint4(u[0], u[1], u[2], u[3]);
      *(uint4*)&As[ar][aseg + 8] = make_uint4(u[4], u[5], u[6], u[7]);
      b_store(bn, bk4, bv1, Bs);
    }
    if (kt + 96 < DDIM) {
#pragma unroll
      for (int j = 0; j < 4; ++j) av1[j] = *(const float4*)(aP + kt + 96 + j * 4);
      b_load<HDIM>(bP, kt + 96, bv1);
    }
    FENCE_BAR;
    g_compute(As, Bs, wr, wc, lane, acc);
    FENCE_BAR;
  }

  const int l15 = lane & 15, rq = (lane >> 4) * 4;
#pragma unroll
  for (int mf = 0; mf < 4; ++mf) {
#pragma unroll
    for (int q = 0; q < 4; ++q) {
      const int r = m0 + wr + mf * 16 + rq + q;
      if (r < n_e) {
        _Float16* hp = hbuf + (size_t)(off + r) * HDIM + n0 + wc + l15;
#pragma unroll
        for (int nf = 0; nf < 4; ++nf) {
          const float v = acc[mf][nf][q];
          hp[nf * 16] = (_Float16)(v / (1.f + __expf(-v)));
        }
      }
    }
  }
}

// ---------------- GEMM2: y[row] = h_e[row] @ W2[e] (unweighted, no atomics) ----------------
__global__ __launch_bounds__(256, 2) void gemm2_k(
    const _Float16* __restrict__ hbuf, const float* __restrict__ W2,
    const int* __restrict__ counts, _Float16* __restrict__ ybuf) {
  const int e = blockIdx.z;
  const int n_e = counts[e * 64];
  const int m0 = blockIdx.y * 128;
  if (m0 >= n_e) return;
  const int n0 = blockIdx.x * 128;
  int off = 0;
#pragma unroll
  for (int i = 0; i < NEXP; ++i) off += (i < e) ? counts[i * 64] : 0;

  __shared__ __align__(16) _Float16 As[128][40];
  __shared__ __align__(16) _Float16 Bs[128][40];

  const int tid = threadIdx.x;
  const int lane = tid & 63;
  const int w = tid >> 6;
  const int wr = (w >> 1) * 64, wc = (w & 1) * 64;

  const int ar = tid >> 1, aseg = (tid & 1) * 16;
  int rA = m0 + ar; if (rA >= n_e) rA = m0;
  const _Float16* aP = hbuf + (size_t)(off + rA) * HDIM + aseg;
  const int bn = tid & 31, bk4 = (tid >> 5) * 4;
  const float* bP = W2 + (size_t)e * HDIM * DDIM + (size_t)bk4 * DDIM + n0 + bn;

  f32x4 acc[4][4] = {};

  uint4 av0[2], av1[2];
  float bv0[4][4], bv1[4][4];
  av0[0] = *(const uint4*)(aP);      av0[1] = *(const uint4*)(aP + 8);
  b_load<DDIM>(bP, 0, bv0);
  av1[0] = *(const uint4*)(aP + 32); av1[1] = *(const uint4*)(aP + 40);
  b_load<DDIM>(bP, 32, bv1);

  for (int kt = 0; kt < HDIM; kt += 64) {
    {
      *(uint4*)&As[ar][aseg]     = av0[0];
      *(uint4*)&As[ar][aseg + 8] = av0[1];
      b_store(bn, bk4, bv0, Bs);
    }
    if (kt + 64 < HDIM) {
      av0[0] = *(const uint4*)(aP + kt + 64);
      av0[1] = *(const uint4*)(aP + kt + 72);
      b_load<DDIM>(bP, kt + 64, bv0);
    }
    FENCE_BAR;
    g_compute(As, Bs, wr, wc, lane, acc);
    FENCE_BAR;
    {
      *(uint4*)&As[ar][aseg]     = av1[0];
      *(uint4*)&As[ar][aseg + 8] = av1[1];
      b_store(bn, bk4, bv1, Bs);
    }
    if (kt + 96 < HDIM) {
      av1[0] = *(const uint4*)(aP + kt + 96);
      av1[1] = *(const uint4*)(aP + kt + 104);
      b_load<DDIM>(bP, kt + 96, bv1);
    }
    FENCE_BAR;
    g_compute(As, Bs, wr, wc, lane, acc);
    FENCE_BAR;
  }

  // epilogue: unweighted y rows, f16, non-atomic (each (row, n-slice) has one writer)
  const int l15 = lane & 15, rq = (lane >> 4) * 4;
#pragma unroll
  for (int mf = 0; mf < 4; ++mf) {
#pragma unroll
    for (int q = 0; q < 4; ++q) {
      const int r = m0 + wr + mf * 16 + rq + q;
      if (r < n_e) {
        _Float16* yp = ybuf + (size_t)(off + r) * DDIM + n0 + wc + l15;
#pragma unroll
        for (int nf = 0; nf < 4; ++nf) yp[nf * 16] = (_Float16)acc[mf][nf][q];
      }
    }
  }
}

// ---------------- Combine: out[t] = w0*y[slot0] + w1*y[slot1] ----------------
__global__ __launch_bounds__(256) void combine_k(
    const _Float16* __restrict__ ybuf, const int* __restrict__ counts,
    const int* __restrict__ slots, const float* __restrict__ weights,
    float* __restrict__ out) {
  const int t = blockIdx.x;
  const int s0 = slots[t * 2], s1 = slots[t * 2 + 1];
  const int e0 = s0 >> 16, p0 = s0 & 0xFFFF;
  const int e1 = s1 >> 16, p1 = s1 & 0xFFFF;
  int off0 = 0, off1 = 0;
#pragma unroll
  for (int i = 0; i < NEXP; ++i) {
    const int c = counts[i * 64];
    off0 += (i < e0) ? c : 0;
    off1 += (i < e1) ? c : 0;
  }
  const float w0 = weights[e0 * TOK + p0];
  const float w1 = weights[e1 * TOK + p1];
  const int col = threadIdx.x * 4;
  const ushort4 u0 = *(const ushort4*)(ybuf + (size_t)(off0 + p0) * DDIM + col);
  const ushort4 u1 = *(const ushort4*)(ybuf + (size_t)(off1 + p1) * DDIM + col);
  float4 o;
  o.x = w0 * (float)__builtin_bit_cast(_Float16, u0.x) + w1 * (float)__builtin_bit_cast(_Float16, u1.x);
  o.y = w0 * (float)__builtin_bit_cast(_Float16, u0.y) + w1 * (float)__builtin_bit_cast(_Float16, u1.y);
  o.z = w0 * (float)__builtin_bit_cast(_Float16, u0.z) + w1 * (float)__builtin_bit_cast(_Float16, u1.z);
  o.w = w0 * (float)__builtin_bit_cast(_Float16, u0.w) + w1 * (float)__builtin_bit_cast(_Float16, u1.w);
  *(float4*)(out + (size_t)t * DDIM + col) = o;
}

// ---------------- Host launch ----------------
extern "C" void kernel_launch(void* const* d_in, const int* in_sizes, int n_in,
                              void* d_out, int out_size, void* d_ws, size_t ws_size,
                              hipStream_t stream) {
  const float* x  = (const float*)d_in[0];
  const float* Wr = (const float*)d_in[1];
  const float* W1 = (const float*)d_in[2];
  const float* W2 = (const float*)d_in[3];
  float* out = (float*)d_out;
  char* ws = (char*)d_ws;

  int*      counts  = (int*)(ws + OFF_COUNTS);
  int*      tokens  = (int*)(ws + OFF_TOKENS);
  float*    weights = (float*)(ws + OFF_WEIGHTS);
  int*      slots   = (int*)(ws + OFF_SLOTS);
  _Float16* hbuf    = (_Float16*)(ws + OFF_H);
  _Float16* ybuf    = (_Float16*)(ws + OFF_Y);

  hipMemsetAsync(counts, 0, 2048, stream);

  router_k<<<TOK / 4, 256, 0, stream>>>(x, Wr, counts, tokens, weights, slots);

  const dim3 g1(HDIM / 128, TOK / 128, NEXP);
  const dim3 g2(DDIM / 128, TOK / 128, NEXP);
  gemm1_k<<<g1, 256, 0, stream>>>(x, W1, counts, tokens, hbuf);
  gemm2_k<<<g2, 256, 0, stream>>>(hbuf, W2, counts, ybuf);
  combine_k<<<TOK, 256, 0, stream>>>(ybuf, counts, slots, weights, out);
}

// Round 9
// 894.785 us; speedup vs baseline: 4.3639x; 1.3301x over previous
//
#include <hip/hip_runtime.h>
#include <hip/hip_bf16.h>

// MoE MLP: B=4, L=2048, D=1024, E=8, H=4096, top-2. T=8192 tokens, 16384 assignments.
// Round 9 (= round 8 resubmit; bench never ran): m97-pattern GEMM cores —
// global_load_lds staging (16B/lane, linear LDS, both-sides XOR swizzle),
// fp32->f16 cvt at fragment-read, per-lane gathered A for gemm1.
// Router/combine/epilogues unchanged (verified r5-r7).
// ws footprint = 1MB meta + 128MB hbuf + 32MB ybuf = 168.8MB (proven by r7 pass).

#define TOK  8192
#define DDIM 1024
#define NEXP 8
#define HDIM 4096

typedef __attribute__((ext_vector_type(8))) _Float16 f16x8;
typedef __attribute__((ext_vector_type(4))) float    f32x4;

static constexpr size_t OFF_COUNTS  = 0;
static constexpr size_t OFF_TOKENS  = 4096;
static constexpr size_t OFF_WEIGHTS = OFF_TOKENS + (size_t)NEXP * TOK * 4;
static constexpr size_t OFF_SLOTS   = OFF_WEIGHTS + (size_t)NEXP * TOK * 4;
static constexpr size_t OFF_H       = 1ull << 20;
static constexpr size_t OFF_Y       = OFF_H + (1ull << 27);

typedef __attribute__((address_space(1))) const void gv_t;
typedef __attribute__((address_space(3))) void lv_t;
__device__ __forceinline__ void gload16(const void* g, void* l) {
  __builtin_amdgcn_global_load_lds((gv_t*)g, (lv_t*)l, 16, 0, 0);
}

__device__ __forceinline__ f16x8 pack8(const float* f) {
  union { f16x8 v; unsigned u[4]; } r;
#pragma unroll
  for (int i = 0; i < 4; ++i)
    r.u[i] = __builtin_bit_cast(unsigned, __builtin_amdgcn_cvt_pkrtz(f[2 * i], f[2 * i + 1]));
  return r.v;
}

// ---------------- Router (verified r1/r5-r7) ----------------
__global__ __launch_bounds__(256) void router_k(
    const float* __restrict__ x, const float* __restrict__ Wr,
    int* __restrict__ counts, int* __restrict__ tokens, float* __restrict__ weights,
    int* __restrict__ slots) {
  const int lane = threadIdx.x & 63;
  const int t = blockIdx.x * 4 + (threadIdx.x >> 6);
  const float* xr = x + (size_t)t * DDIM;

  float acc[NEXP];
#pragma unroll
  for (int e = 0; e < NEXP; ++e) acc[e] = 0.f;

#pragma unroll
  for (int it = 0; it < DDIM / 256; ++it) {
    const int d = it * 256 + lane * 4;
    const float4 xv = *(const float4*)(xr + d);
    const float* wr = Wr + (size_t)d * NEXP;
#pragma unroll
    for (int j = 0; j < 4; ++j) {
      const float xs = (j == 0) ? xv.x : (j == 1) ? xv.y : (j == 2) ? xv.z : xv.w;
      const float4 w0 = *(const float4*)(wr + j * NEXP);
      const float4 w1 = *(const float4*)(wr + j * NEXP + 4);
      acc[0] = fmaf(xs, w0.x, acc[0]); acc[1] = fmaf(xs, w0.y, acc[1]);
      acc[2] = fmaf(xs, w0.z, acc[2]); acc[3] = fmaf(xs, w0.w, acc[3]);
      acc[4] = fmaf(xs, w1.x, acc[4]); acc[5] = fmaf(xs, w1.y, acc[5]);
      acc[6] = fmaf(xs, w1.z, acc[6]); acc[7] = fmaf(xs, w1.w, acc[7]);
    }
  }
#pragma unroll
  for (int e = 0; e < NEXP; ++e) {
#pragma unroll
    for (int off = 32; off > 0; off >>= 1) acc[e] += __shfl_xor(acc[e], off);
  }
  if (lane == 0) {
    int i0 = 0; float v0 = acc[0];
#pragma unroll
    for (int e = 1; e < NEXP; ++e) if (acc[e] > v0) { v0 = acc[e]; i0 = e; }
    int i1 = -1; float v1 = -3.4e38f;
#pragma unroll
    for (int e = 0; e < NEXP; ++e) if (e != i0 && acc[e] > v1) { v1 = acc[e]; i1 = e; }
    const float r = expf(v1 - v0);
    const float inv = 1.f / (1.f + r);
    const int p0 = atomicAdd(counts + i0 * 64, 1);
    tokens[i0 * TOK + p0] = t; weights[i0 * TOK + p0] = inv;
    const int p1 = atomicAdd(counts + i1 * 64, 1);
    tokens[i1 * TOK + p1] = t; weights[i1 * TOK + p1] = r * inv;
    slots[t * 2]     = (i0 << 16) | p0;
    slots[t * 2 + 1] = (i1 << 16) | p1;
  }
}

// ---------------- GEMM1: h = silu(gather(x) @ W1[e]) ----------------
// 128x128 tile, BK=32. A: fp32 [128][32] (128B rows, chunk swz c^=(r&7)).
// B: fp32 [32][128] (512B rows, dword-col swz n^=((k>>3&1)<<4)). Both gload_lds.
__global__ __launch_bounds__(256) void gemm1_k(
    const float* __restrict__ x, const float* __restrict__ W1,
    const int* __restrict__ counts, const int* __restrict__ tokens,
    _Float16* __restrict__ hbuf) {
  const int e = blockIdx.z;
  const int n_e = counts[e * 64];
  const int m0 = blockIdx.y * 128;
  if (m0 >= n_e) return;
  const int n0 = blockIdx.x * 128;
  int off = 0;
#pragma unroll
  for (int i = 0; i < NEXP; ++i) off += (i < e) ? counts[i * 64] : 0;

  __shared__ __align__(16) float Asf[128][32];
  __shared__ __align__(16) float Bsf[32][128];

  const int tid = threadIdx.x, lane = tid & 63, w = tid >> 6;
  const int wr = (w >> 1) * 64, wc = (w & 1) * 64;

  // A staging: wave w -> rows [w*32, w*32+32), 4 instrs x 8 rows (1KB each)
  const int arow_l = (w << 5) + (lane >> 3);          // + i*8
  const int agc = (lane & 7) ^ (lane >> 3);           // pre-swizzled source chunk
  int atok[4];
#pragma unroll
  for (int i = 0; i < 4; ++i) {
    const int r = m0 + arow_l + i * 8;
    atok[i] = (r < n_e) ? tokens[e * TOK + r] : 0;
  }
  // B staging: wave w -> k rows [w*8, w*8+8), 4 instrs x 2 rows
  const int bk_l = (w << 3) + (lane >> 5);            // + i*2
  const int bgc = (lane & 31) ^ ((w & 1) << 2);       // pre-swizzled source chunk
  const float* Wb = W1 + (size_t)e * DDIM * HDIM + n0;

  f32x4 acc[4][4] = {};
  const int l15 = lane & 15, hi = lane >> 4;

  for (int kt = 0; kt < DDIM; kt += 32) {
#pragma unroll
    for (int i = 0; i < 4; ++i)
      gload16(x + (size_t)atok[i] * DDIM + kt + agc * 4, &Asf[(w << 5) + i * 8][0]);
#pragma unroll
    for (int i = 0; i < 4; ++i)
      gload16(Wb + (size_t)(kt + bk_l + i * 2) * HDIM + bgc * 4, &Bsf[(w << 3) + i * 2][0]);
    __syncthreads();
    f16x8 af[4], bf[4];
#pragma unroll
    for (int mf = 0; mf < 4; ++mf) {
      const int r = wr + mf * 16 + l15, s = r & 7;
      float fa[8];
      *(float4*)&fa[0] = *(const float4*)&Asf[r][(((hi << 1)    ) ^ s) << 2];
      *(float4*)&fa[4] = *(const float4*)&Asf[r][(((hi << 1) | 1) ^ s) << 2];
      af[mf] = pack8(fa);
    }
#pragma unroll
    for (int nf = 0; nf < 4; ++nf) {
      const int n = (wc + nf * 16 + l15) ^ ((hi & 1) << 4);
      float fb[8];
#pragma unroll
      for (int j = 0; j < 8; ++j) fb[j] = Bsf[(hi << 3) + j][n];
      bf[nf] = pack8(fb);
    }
#pragma unroll
    for (int mf = 0; mf < 4; ++mf)
#pragma unroll
      for (int nf = 0; nf < 4; ++nf)
        acc[mf][nf] = __builtin_amdgcn_mfma_f32_16x16x32_f16(af[mf], bf[nf], acc[mf][nf], 0, 0, 0);
    __syncthreads();
  }

  // epilogue: SiLU -> f16 h rows. C/D: col=lane&15, row=(lane>>4)*4+q (verified).
  const int rq = hi * 4;
#pragma unroll
  for (int mf = 0; mf < 4; ++mf) {
#pragma unroll
    for (int q = 0; q < 4; ++q) {
      const int r = m0 + wr + mf * 16 + rq + q;
      if (r < n_e) {
        _Float16* hp = hbuf + (size_t)(off + r) * HDIM + n0 + wc + l15;
#pragma unroll
        for (int nf = 0; nf < 4; ++nf) {
          const float v = acc[mf][nf][q];
          hp[nf * 16] = (_Float16)(v / (1.f + __expf(-v)));
        }
      }
    }
  }
}

// ---------------- GEMM2: y[row] = h_e[row] @ W2[e] ----------------
// A: f16 [128][32] (64B rows, chunk swz c^=(r&3)). B: fp32 [32][128] as gemm1.
__global__ __launch_bounds__(256) void gemm2_k(
    const _Float16* __restrict__ hbuf, const float* __restrict__ W2,
    const int* __restrict__ counts, _Float16* __restrict__ ybuf) {
  const int e = blockIdx.z;
  const int n_e = counts[e * 64];
  const int m0 = blockIdx.y * 128;
  if (m0 >= n_e) return;
  const int n0 = blockIdx.x * 128;
  int off = 0;
#pragma unroll
  for (int i = 0; i < NEXP; ++i) off += (i < e) ? counts[i * 64] : 0;

  __shared__ __align__(16) _Float16 As2[128][32];
  __shared__ __align__(16) float    Bsf[32][128];

  const int tid = threadIdx.x, lane = tid & 63, w = tid >> 6;
  const int wr = (w >> 1) * 64, wc = (w & 1) * 64;

  // A staging: wave w -> rows [w*32,+32), 2 instrs x 16 rows (1KB = 16 x 64B rows)
  const int arow_l = (w << 5) + (lane >> 2);          // + i*16
  const int agc = (lane & 3) ^ ((lane >> 2) & 3);     // pre-swizzled source chunk
  const _Float16* Ab = hbuf + (size_t)(off + m0) * HDIM;
  // B staging: as gemm1, N=DDIM
  const int bk_l = (w << 3) + (lane >> 5);
  const int bgc = (lane & 31) ^ ((w & 1) << 2);
  const float* Wb = W2 + (size_t)e * HDIM * DDIM + n0;

  f32x4 acc[4][4] = {};
  const int l15 = lane & 15, hi = lane >> 4;

  for (int kt = 0; kt < HDIM; kt += 32) {
#pragma unroll
    for (int i = 0; i < 2; ++i)
      gload16(Ab + (size_t)(arow_l + i * 16) * HDIM + kt + agc * 8, &As2[(w << 5) + i * 16][0]);
#pragma unroll
    for (int i = 0; i < 4; ++i)
      gload16(Wb + (size_t)(kt + bk_l + i * 2) * DDIM + bgc * 4, &Bsf[(w << 3) + i * 2][0]);
    __syncthreads();
    f16x8 af[4], bf[4];
#pragma unroll
    for (int mf = 0; mf < 4; ++mf) {
      const int r = wr + mf * 16 + l15;
      af[mf] = *(const f16x8*)&As2[r][(hi ^ (r & 3)) << 3];
    }
#pragma unroll
    for (int nf = 0; nf < 4; ++nf) {
      const int n = (wc + nf * 16 + l15) ^ ((hi & 1) << 4);
      float fb[8];
#pragma unroll
      for (int j = 0; j < 8; ++j) fb[j] = Bsf[(hi << 3) + j][n];
      bf[nf] = pack8(fb);
    }
#pragma unroll
    for (int mf = 0; mf < 4; ++mf)
#pragma unroll
      for (int nf = 0; nf < 4; ++nf)
        acc[mf][nf] = __builtin_amdgcn_mfma_f32_16x16x32_f16(af[mf], bf[nf], acc[mf][nf], 0, 0, 0);
    __syncthreads();
  }

  // epilogue: unweighted y rows, f16 (verified r7)
  const int rq = hi * 4;
#pragma unroll
  for (int mf = 0; mf < 4; ++mf) {
#pragma unroll
    for (int q = 0; q < 4; ++q) {
      const int r = m0 + wr + mf * 16 + rq + q;
      if (r < n_e) {
        _Float16* yp = ybuf + (size_t)(off + r) * DDIM + n0 + wc + l15;
#pragma unroll
        for (int nf = 0; nf < 4; ++nf) yp[nf * 16] = (_Float16)acc[mf][nf][q];
      }
    }
  }
}

// ---------------- Combine: out[t] = w0*y[slot0] + w1*y[slot1] (verified r7) ----------------
__global__ __launch_bounds__(256) void combine_k(
    const _Float16* __restrict__ ybuf, const int* __restrict__ counts,
    const int* __restrict__ slots, const float* __restrict__ weights,
    float* __restrict__ out) {
  const int t = blockIdx.x;
  const int s0 = slots[t * 2], s1 = slots[t * 2 + 1];
  const int e0 = s0 >> 16, p0 = s0 & 0xFFFF;
  const int e1 = s1 >> 16, p1 = s1 & 0xFFFF;
  int off0 = 0, off1 = 0;
#pragma unroll
  for (int i = 0; i < NEXP; ++i) {
    const int c = counts[i * 64];
    off0 += (i < e0) ? c : 0;
    off1 += (i < e1) ? c : 0;
  }
  const float w0 = weights[e0 * TOK + p0];
  const float w1 = weights[e1 * TOK + p1];
  const int col = threadIdx.x * 4;
  const ushort4 u0 = *(const ushort4*)(ybuf + (size_t)(off0 + p0) * DDIM + col);
  const ushort4 u1 = *(const ushort4*)(ybuf + (size_t)(off1 + p1) * DDIM + col);
  float4 o;
  o.x = w0 * (float)__builtin_bit_cast(_Float16, u0.x) + w1 * (float)__builtin_bit_cast(_Float16, u1.x);
  o.y = w0 * (float)__builtin_bit_cast(_Float16, u0.y) + w1 * (float)__builtin_bit_cast(_Float16, u1.y);
  o.z = w0 * (float)__builtin_bit_cast(_Float16, u0.z) + w1 * (float)__builtin_bit_cast(_Float16, u1.z);
  o.w = w0 * (float)__builtin_bit_cast(_Float16, u0.w) + w1 * (float)__builtin_bit_cast(_Float16, u1.w);
  *(float4*)(out + (size_t)t * DDIM + col) = o;
}

// ---------------- Host launch ----------------
extern "C" void kernel_launch(void* const* d_in, const int* in_sizes, int n_in,
                              void* d_out, int out_size, void* d_ws, size_t ws_size,
                              hipStream_t stream) {
  const float* x  = (const float*)d_in[0];
  const float* Wr = (const float*)d_in[1];
  const float* W1 = (const float*)d_in[2];
  const float* W2 = (const float*)d_in[3];
  float* out = (float*)d_out;
  char* ws = (char*)d_ws;

  int*      counts  = (int*)(ws + OFF_COUNTS);
  int*      tokens  = (int*)(ws + OFF_TOKENS);
  float*    weights = (float*)(ws + OFF_WEIGHTS);
  int*      slots   = (int*)(ws + OFF_SLOTS);
  _Float16* hbuf    = (_Float16*)(ws + OFF_H);
  _Float16* ybuf    = (_Float16*)(ws + OFF_Y);

  hipMemsetAsync(counts, 0, 2048, stream);

  router_k<<<TOK / 4, 256, 0, stream>>>(x, Wr, counts, tokens, weights, slots);

  const dim3 g1(HDIM / 128, TOK / 128, NEXP);
  const dim3 g2(DDIM / 128, TOK / 128, NEXP);
  gemm1_k<<<g1, 256, 0, stream>>>(x, W1, counts, tokens, hbuf);
  gemm2_k<<<g2, 256, 0, stream>>>(hbuf, W2, counts, ybuf);
  combine_k<<<TOK, 256, 0, stream>>>(ybuf, counts, slots, weights, out);
}

// Round 10
// 867.699 us; speedup vs baseline: 4.5001x; 1.0312x over previous
//
#include <hip/hip_runtime.h>
#include <hip/hip_bf16.h>

// MoE MLP: B=4, L=2048, D=1024, E=8, H=4096, top-2. T=8192 tokens, 16384 assignments.
// Round 10: merge r5's conflict-free f16 [row][40] LDS fragment layout (ds_read_b128
// A and B) with a 2-deep double-buffered pipeline (loads for t+1 issued before
// compute of t; one __syncthreads per K-step). B reg-staged+transposed (r6 pattern),
// gemm1 A gathered+cvt, gemm2 A f16 direct. Router/combine/epilogues verified r5-r9.

#define TOK  8192
#define DDIM 1024
#define NEXP 8
#define HDIM 4096

typedef __attribute__((ext_vector_type(8))) _Float16 f16x8;
typedef __attribute__((ext_vector_type(4))) float    f32x4;

static constexpr size_t OFF_COUNTS  = 0;
static constexpr size_t OFF_TOKENS  = 4096;
static constexpr size_t OFF_WEIGHTS = OFF_TOKENS + (size_t)NEXP * TOK * 4;
static constexpr size_t OFF_SLOTS   = OFF_WEIGHTS + (size_t)NEXP * TOK * 4;
static constexpr size_t OFF_H       = 1ull << 20;
static constexpr size_t OFF_Y       = OFF_H + (1ull << 27);

// ---------------- Router (verified r1/r5-r9) ----------------
__global__ __launch_bounds__(256) void router_k(
    const float* __restrict__ x, const float* __restrict__ Wr,
    int* __restrict__ counts, int* __restrict__ tokens, float* __restrict__ weights,
    int* __restrict__ slots) {
  const int lane = threadIdx.x & 63;
  const int t = blockIdx.x * 4 + (threadIdx.x >> 6);
  const float* xr = x + (size_t)t * DDIM;

  float acc[NEXP];
#pragma unroll
  for (int e = 0; e < NEXP; ++e) acc[e] = 0.f;

#pragma unroll
  for (int it = 0; it < DDIM / 256; ++it) {
    const int d = it * 256 + lane * 4;
    const float4 xv = *(const float4*)(xr + d);
    const float* wr = Wr + (size_t)d * NEXP;
#pragma unroll
    for (int j = 0; j < 4; ++j) {
      const float xs = (j == 0) ? xv.x : (j == 1) ? xv.y : (j == 2) ? xv.z : xv.w;
      const float4 w0 = *(const float4*)(wr + j * NEXP);
      const float4 w1 = *(const float4*)(wr + j * NEXP + 4);
      acc[0] = fmaf(xs, w0.x, acc[0]); acc[1] = fmaf(xs, w0.y, acc[1]);
      acc[2] = fmaf(xs, w0.z, acc[2]); acc[3] = fmaf(xs, w0.w, acc[3]);
      acc[4] = fmaf(xs, w1.x, acc[4]); acc[5] = fmaf(xs, w1.y, acc[5]);
      acc[6] = fmaf(xs, w1.z, acc[6]); acc[7] = fmaf(xs, w1.w, acc[7]);
    }
  }
#pragma unroll
  for (int e = 0; e < NEXP; ++e) {
#pragma unroll
    for (int off = 32; off > 0; off >>= 1) acc[e] += __shfl_xor(acc[e], off);
  }
  if (lane == 0) {
    int i0 = 0; float v0 = acc[0];
#pragma unroll
    for (int e = 1; e < NEXP; ++e) if (acc[e] > v0) { v0 = acc[e]; i0 = e; }
    int i1 = -1; float v1 = -3.4e38f;
#pragma unroll
    for (int e = 0; e < NEXP; ++e) if (e != i0 && acc[e] > v1) { v1 = acc[e]; i1 = e; }
    const float r = expf(v1 - v0);
    const float inv = 1.f / (1.f + r);
    const int p0 = atomicAdd(counts + i0 * 64, 1);
    tokens[i0 * TOK + p0] = t; weights[i0 * TOK + p0] = inv;
    const int p1 = atomicAdd(counts + i1 * 64, 1);
    tokens[i1 * TOK + p1] = t; weights[i1 * TOK + p1] = r * inv;
    slots[t * 2]     = (i0 << 16) | p0;
    slots[t * 2 + 1] = (i1 << 16) | p1;
  }
}

// LDS tiles [row][40] f16 (80B stride): fragment ds_read_b128 ~2-way (free);
// staged writes ~4-way. Verified r5/r6.

template <int LD>
__device__ __forceinline__ void b_load(const float* bP, int kt, float (&bv)[4][4]) {
#pragma unroll
  for (int g = 0; g < 4; ++g)
#pragma unroll
    for (int j = 0; j < 4; ++j)
      bv[g][j] = bP[(size_t)(kt + j) * LD + 32 * g];
}

__device__ __forceinline__ void b_store(int bn, int bk4, const float (&bv)[4][4],
                                        _Float16 (*Bs)[40]) {
#pragma unroll
  for (int g = 0; g < 4; ++g) {
    const unsigned p0 = __builtin_bit_cast(unsigned, __builtin_amdgcn_cvt_pkrtz(bv[g][0], bv[g][1]));
    const unsigned p1 = __builtin_bit_cast(unsigned, __builtin_amdgcn_cvt_pkrtz(bv[g][2], bv[g][3]));
    *(uint2*)&Bs[bn + 32 * g][bk4] = make_uint2(p0, p1);
  }
}

__device__ __forceinline__ void a1_store(const float4 (&av)[4], int ar, int aseg,
                                         _Float16 (*As)[40]) {
  unsigned u[8];
#pragma unroll
  for (int j = 0; j < 4; ++j) {
    u[j * 2]     = __builtin_bit_cast(unsigned, __builtin_amdgcn_cvt_pkrtz(av[j].x, av[j].y));
    u[j * 2 + 1] = __builtin_bit_cast(unsigned, __builtin_amdgcn_cvt_pkrtz(av[j].z, av[j].w));
  }
  *(uint4*)&As[ar][aseg]     = make_uint4(u[0], u[1], u[2], u[3]);
  *(uint4*)&As[ar][aseg + 8] = make_uint4(u[4], u[5], u[6], u[7]);
}

// Fragment read + 16 MFMA (layouts HW-verified r5-r7).
__device__ __forceinline__ void g_compute(const _Float16 (*As)[40], const _Float16 (*Bs)[40],
                                          int wr, int wc, int lane, f32x4 (&acc)[4][4]) {
  const int l15 = lane & 15, g8 = (lane >> 4) * 8;
  f16x8 af[4], bf[4];
#pragma unroll
  for (int mf = 0; mf < 4; ++mf) af[mf] = *(const f16x8*)&As[wr + mf * 16 + l15][g8];
#pragma unroll
  for (int nf = 0; nf < 4; ++nf) bf[nf] = *(const f16x8*)&Bs[wc + nf * 16 + l15][g8];
#pragma unroll
  for (int mf = 0; mf < 4; ++mf)
#pragma unroll
    for (int nf = 0; nf < 4; ++nf)
      acc[mf][nf] = __builtin_amdgcn_mfma_f32_16x16x32_f16(af[mf], bf[nf], acc[mf][nf], 0, 0, 0);
}

// ---------------- GEMM1: h = silu(gather(x) @ W1[e]) ----------------
__global__ __launch_bounds__(256) void gemm1_k(
    const float* __restrict__ x, const float* __restrict__ W1,
    const int* __restrict__ counts, const int* __restrict__ tokens,
    _Float16* __restrict__ hbuf) {
  const int e = blockIdx.z;
  const int n_e = counts[e * 64];
  const int m0 = blockIdx.y * 128;
  if (m0 >= n_e) return;
  const int n0 = blockIdx.x * 128;
  int off = 0;
#pragma unroll
  for (int i = 0; i < NEXP; ++i) off += (i < e) ? counts[i * 64] : 0;

  __shared__ __align__(16) _Float16 As[2][128][40];   // 10KB x2
  __shared__ __align__(16) _Float16 Bs[2][128][40];   // 10KB x2  -> 40KB total

  const int tid = threadIdx.x, lane = tid & 63, w = tid >> 6;
  const int wr = (w >> 1) * 64, wc = (w & 1) * 64;

  const int ar = tid >> 1, aseg = (tid & 1) * 16;
  const int rA = m0 + ar;
  const int tokA = (rA < n_e) ? tokens[e * TOK + rA] : 0;
  const float* aP = x + (size_t)tokA * DDIM + aseg;
  const int bn = tid & 31, bk4 = (tid >> 5) * 4;
  const float* bP = W1 + (size_t)e * DDIM * HDIM + (size_t)bk4 * HDIM + n0 + bn;

  f32x4 acc[4][4] = {};

  float4 av[4]; float bv[4][4];
#pragma unroll
  for (int j = 0; j < 4; ++j) av[j] = *(const float4*)(aP + j * 4);
  b_load<HDIM>(bP, 0, bv);
  a1_store(av, ar, aseg, As[0]);
  b_store(bn, bk4, bv, Bs[0]);
  __syncthreads();

  int cur = 0;
  for (int t = 0; t < DDIM / 32 - 1; ++t) {
    const int kn = (t + 1) * 32;
#pragma unroll
    for (int j = 0; j < 4; ++j) av[j] = *(const float4*)(aP + kn + j * 4);
    b_load<HDIM>(bP, kn, bv);
    g_compute(As[cur], Bs[cur], wr, wc, lane, acc);
    a1_store(av, ar, aseg, As[cur ^ 1]);
    b_store(bn, bk4, bv, Bs[cur ^ 1]);
    __syncthreads();
    cur ^= 1;
  }
  g_compute(As[cur], Bs[cur], wr, wc, lane, acc);

  // epilogue: SiLU -> f16 h rows. C/D: col=lane&15, row=(lane>>4)*4+q (verified).
  const int l15 = lane & 15, rq = (lane >> 4) * 4;
#pragma unroll
  for (int mf = 0; mf < 4; ++mf) {
#pragma unroll
    for (int q = 0; q < 4; ++q) {
      const int r = m0 + wr + mf * 16 + rq + q;
      if (r < n_e) {
        _Float16* hp = hbuf + (size_t)(off + r) * HDIM + n0 + wc + l15;
#pragma unroll
        for (int nf = 0; nf < 4; ++nf) {
          const float v = acc[mf][nf][q];
          hp[nf * 16] = (_Float16)(v / (1.f + __expf(-v)));
        }
      }
    }
  }
}

// ---------------- GEMM2: y[row] = h_e[row] @ W2[e] ----------------
__global__ __launch_bounds__(256) void gemm2_k(
    const _Float16* __restrict__ hbuf, const float* __restrict__ W2,
    const int* __restrict__ counts, _Float16* __restrict__ ybuf) {
  const int e = blockIdx.z;
  const int n_e = counts[e * 64];
  const int m0 = blockIdx.y * 128;
  if (m0 >= n_e) return;
  const int n0 = blockIdx.x * 128;
  int off = 0;
#pragma unroll
  for (int i = 0; i < NEXP; ++i) off += (i < e) ? counts[i * 64] : 0;

  __shared__ __align__(16) _Float16 As[2][128][40];
  __shared__ __align__(16) _Float16 Bs[2][128][40];

  const int tid = threadIdx.x, lane = tid & 63, w = tid >> 6;
  const int wr = (w >> 1) * 64, wc = (w & 1) * 64;

  const int ar = tid >> 1, aseg = (tid & 1) * 16;
  int rA = m0 + ar; if (rA >= n_e) rA = m0;   // clamp to a valid h row
  const _Float16* aP = hbuf + (size_t)(off + rA) * HDIM + aseg;
  const int bn = tid & 31, bk4 = (tid >> 5) * 4;
  const float* bP = W2 + (size_t)e * HDIM * DDIM + (size_t)bk4 * DDIM + n0 + bn;

  f32x4 acc[4][4] = {};

  uint4 av[2]; float bv[4][4];
  av[0] = *(const uint4*)(aP); av[1] = *(const uint4*)(aP + 8);
  b_load<DDIM>(bP, 0, bv);
  *(uint4*)&As[0][ar][aseg]     = av[0];
  *(uint4*)&As[0][ar][aseg + 8] = av[1];
  b_store(bn, bk4, bv, Bs[0]);
  __syncthreads();

  int cur = 0;
  for (int t = 0; t < HDIM / 32 - 1; ++t) {
    const int kn = (t + 1) * 32;
    av[0] = *(const uint4*)(aP + kn);
    av[1] = *(const uint4*)(aP + kn + 8);
    b_load<DDIM>(bP, kn, bv);
    g_compute(As[cur], Bs[cur], wr, wc, lane, acc);
    *(uint4*)&As[cur ^ 1][ar][aseg]     = av[0];
    *(uint4*)&As[cur ^ 1][ar][aseg + 8] = av[1];
    b_store(bn, bk4, bv, Bs[cur ^ 1]);
    __syncthreads();
    cur ^= 1;
  }
  g_compute(As[cur], Bs[cur], wr, wc, lane, acc);

  // epilogue: unweighted y rows, f16 (verified r7/r9)
  const int l15 = lane & 15, rq = (lane >> 4) * 4;
#pragma unroll
  for (int mf = 0; mf < 4; ++mf) {
#pragma unroll
    for (int q = 0; q < 4; ++q) {
      const int r = m0 + wr + mf * 16 + rq + q;
      if (r < n_e) {
        _Float16* yp = ybuf + (size_t)(off + r) * DDIM + n0 + wc + l15;
#pragma unroll
        for (int nf = 0; nf < 4; ++nf) yp[nf * 16] = (_Float16)acc[mf][nf][q];
      }
    }
  }
}

// ---------------- Combine: out[t] = w0*y[slot0] + w1*y[slot1] (verified r7/r9) ----------------
__global__ __launch_bounds__(256) void combine_k(
    const _Float16* __restrict__ ybuf, const int* __restrict__ counts,
    const int* __restrict__ slots, const float* __restrict__ weights,
    float* __restrict__ out) {
  const int t = blockIdx.x;
  const int s0 = slots[t * 2], s1 = slots[t * 2 + 1];
  const int e0 = s0 >> 16, p0 = s0 & 0xFFFF;
  const int e1 = s1 >> 16, p1 = s1 & 0xFFFF;
  int off0 = 0, off1 = 0;
#pragma unroll
  for (int i = 0; i < NEXP; ++i) {
    const int c = counts[i * 64];
    off0 += (i < e0) ? c : 0;
    off1 += (i < e1) ? c : 0;
  }
  const float w0 = weights[e0 * TOK + p0];
  const float w1 = weights[e1 * TOK + p1];
  const int col = threadIdx.x * 4;
  const ushort4 u0 = *(const ushort4*)(ybuf + (size_t)(off0 + p0) * DDIM + col);
  const ushort4 u1 = *(const ushort4*)(ybuf + (size_t)(off1 + p1) * DDIM + col);
  float4 o;
  o.x = w0 * (float)__builtin_bit_cast(_Float16, u0.x) + w1 * (float)__builtin_bit_cast(_Float16, u1.x);
  o.y = w0 * (float)__builtin_bit_cast(_Float16, u0.y) + w1 * (float)__builtin_bit_cast(_Float16, u1.y);
  o.z = w0 * (float)__builtin_bit_cast(_Float16, u0.z) + w1 * (float)__builtin_bit_cast(_Float16, u1.z);
  o.w = w0 * (float)__builtin_bit_cast(_Float16, u0.w) + w1 * (float)__builtin_bit_cast(_Float16, u1.w);
  *(float4*)(out + (size_t)t * DDIM + col) = o;
}

// ---------------- Host launch ----------------
extern "C" void kernel_launch(void* const* d_in, const int* in_sizes, int n_in,
                              void* d_out, int out_size, void* d_ws, size_t ws_size,
                              hipStream_t stream) {
  const float* x  = (const float*)d_in[0];
  const float* Wr = (const float*)d_in[1];
  const float* W1 = (const float*)d_in[2];
  const float* W2 = (const float*)d_in[3];
  float* out = (float*)d_out;
  char* ws = (char*)d_ws;

  int*      counts  = (int*)(ws + OFF_COUNTS);
  int*      tokens  = (int*)(ws + OFF_TOKENS);
  float*    weights = (float*)(ws + OFF_WEIGHTS);
  int*      slots   = (int*)(ws + OFF_SLOTS);
  _Float16* hbuf    = (_Float16*)(ws + OFF_H);
  _Float16* ybuf    = (_Float16*)(ws + OFF_Y);

  hipMemsetAsync(counts, 0, 2048, stream);

  router_k<<<TOK / 4, 256, 0, stream>>>(x, Wr, counts, tokens, weights, slots);

  const dim3 g1(HDIM / 128, TOK / 128, NEXP);
  const dim3 g2(DDIM / 128, TOK / 128, NEXP);
  gemm1_k<<<g1, 256, 0, stream>>>(x, W1, counts, tokens, hbuf);
  gemm2_k<<<g2, 256, 0, stream>>>(hbuf, W2, counts, ybuf);
  combine_k<<<TOK, 256, 0, stream>>>(ybuf, counts, slots, weights, out);
}